// Round 3
// baseline (580.345 us; speedup 1.0000x reference)
//
#include <hip/hip_runtime.h>
#include <math.h>

#define DD 128
#define HH 256

typedef __attribute__((ext_vector_type(8))) short bf16x8;
typedef __attribute__((ext_vector_type(4))) float f32x4;
typedef unsigned short u16;
typedef unsigned int u32;

__device__ __forceinline__ float bf2f(u16 u) {
  union { u32 i; float f; } v; v.i = ((u32)u) << 16; return v.f;
}
__device__ __forceinline__ u16 f2bf(float f) {
  union { u32 i; float f; } v; v.f = f;
  u32 r = v.i + 0x7FFFu + ((v.i >> 16) & 1u);
  return (u16)(r >> 16);
}
__device__ __forceinline__ u32 pack2(float a, float b) {
  return (u32)f2bf(a) | ((u32)f2bf(b) << 16);
}

// vectorized f32 -> bf16 (8 elems/thread)
__global__ __launch_bounds__(256) void conv8_f32_bf16(const float* __restrict__ in,
                                                      uint4* __restrict__ out, int n8) {
  int i = blockIdx.x * 256 + threadIdx.x;
  int stride = gridDim.x * 256;
  for (; i < n8; i += stride) {
    const float4 a = ((const float4*)in)[i * 2];
    const float4 b = ((const float4*)in)[i * 2 + 1];
    out[i] = make_uint4(pack2(a.x, a.y), pack2(a.z, a.w),
                        pack2(b.x, b.y), pack2(b.z, b.w));
  }
}

// vectorized sigmoid(f32) -> bf16
__global__ __launch_bounds__(256) void sigmoid8_f32_bf16(const float* __restrict__ in,
                                                         uint4* __restrict__ out, int n8) {
  int i = blockIdx.x * 256 + threadIdx.x;
  int stride = gridDim.x * 256;
  for (; i < n8; i += stride) {
    const float4 a = ((const float4*)in)[i * 2];
    const float4 b = ((const float4*)in)[i * 2 + 1];
    float s0 = 1.f / (1.f + __expf(-a.x));
    float s1 = 1.f / (1.f + __expf(-a.y));
    float s2 = 1.f / (1.f + __expf(-a.z));
    float s3 = 1.f / (1.f + __expf(-a.w));
    float s4 = 1.f / (1.f + __expf(-b.x));
    float s5 = 1.f / (1.f + __expf(-b.y));
    float s6 = 1.f / (1.f + __expf(-b.z));
    float s7 = 1.f / (1.f + __expf(-b.w));
    out[i] = make_uint4(pack2(s0, s1), pack2(s2, s3), pack2(s4, s5), pack2(s6, s7));
  }
}

// weight transpose + convert: in [K][N] f32 -> out [N][K] bf16
__global__ __launch_bounds__(256) void transpose_w(const float* __restrict__ in,
                                                   u16* __restrict__ out, int K, int N) {
  int idx = blockIdx.x * 256 + threadIdx.x;
  int total = K * N;
  int stride = gridDim.x * 256;
  for (; idx < total; idx += stride) {
    int k = idx / N, n = idx % N;
    out[n * K + k] = f2bf(in[idx]);
  }
}

// tiny FCNN on the global feature vector (fp32, one block)
__global__ __launch_bounds__(256) void g3_kernel(const float* __restrict__ g,
    const float* __restrict__ W3a, const float* __restrict__ b3a,
    const float* __restrict__ W3b, const float* __restrict__ b3b,
    float* __restrict__ g3out) {
  __shared__ float gs[DD];
  __shared__ float hs[HH];
  int t = threadIdx.x;
  if (t < DD) gs[t] = g[t];
  __syncthreads();
  float acc = b3a[t];
  for (int k = 0; k < DD; ++k) acc = fmaf(gs[k], W3a[k * HH + t], acc);
  hs[t] = acc > 0.f ? acc : 0.f;
  __syncthreads();
  if (t < DD) {
    float o = b3b[t];
    for (int j = 0; j < HH; ++j) o = fmaf(hs[j], W3b[j * DD + t], o);
    g3out[t] = o;
  }
}

// C[M,NCOLS] = A[M,K] @ B[K,NCOLS] + bias (optional relu).
// BT is B transposed [NCOLS][K] bf16 so fragments load as bf16x8.
// One wave computes 16 rows x 64 cols (4 accumulators share each A fragment).
template<int K, int NCOLS, bool RELU>
__global__ __launch_bounds__(256) void gemm_w64(const u16* __restrict__ A,
    const u16* __restrict__ BT, const float* __restrict__ bias,
    u16* __restrict__ Dst, int M) {
  const int wave = (blockIdx.x * 256 + threadIdx.x) >> 6;
  const int lane = threadIdx.x & 63;
  const int totalWaves = (gridDim.x * 256) >> 6;
  constexpr int nChunks = NCOLS / 64;
  const int nc = wave % nChunks;
  const int mw = wave / nChunks;
  const int mStride = totalWaves / nChunks;
  const int l15 = lane & 15;
  const int l4 = lane >> 4;
  constexpr int KB = K / 32;

  bf16x8 bfrag[KB][4];
  float bcol[4];
#pragma unroll
  for (int t = 0; t < 4; ++t) {
    const int col = nc * 64 + t * 16 + l15;
    const u16* bbase = BT + (size_t)col * K + l4 * 8;
#pragma unroll
    for (int kb = 0; kb < KB; ++kb) bfrag[kb][t] = *(const bf16x8*)(bbase + kb * 32);
    bcol[t] = bias[col];
  }

  const int mTiles = M >> 4;  // M is a multiple of 16 here
  for (int mt = mw; mt < mTiles; mt += mStride) {
    const int m0 = mt << 4;
    const u16* arow = A + (size_t)(m0 + l15) * K + l4 * 8;
    f32x4 acc[4] = {{0,0,0,0},{0,0,0,0},{0,0,0,0},{0,0,0,0}};
#pragma unroll
    for (int kb = 0; kb < KB; ++kb) {
      bf16x8 afrag = *(const bf16x8*)(arow + kb * 32);
#pragma unroll
      for (int t = 0; t < 4; ++t)
        acc[t] = __builtin_amdgcn_mfma_f32_16x16x32_bf16(afrag, bfrag[kb][t], acc[t], 0, 0, 0);
    }
#pragma unroll
    for (int t = 0; t < 4; ++t) {
#pragma unroll
      for (int r = 0; r < 4; ++r) {
        const int row = m0 + l4 * 4 + r;
        float v = acc[t][r] + bcol[t];
        if (RELU) v = v > 0.f ? v : 0.f;
        Dst[(size_t)row * NCOLS + nc * 64 + t * 16 + l15] = f2bf(v);
      }
    }
  }
}

// ---- CSR build ----
__global__ __launch_bounds__(256) void count_kernel(const int* __restrict__ eix,
                                                    u32* __restrict__ deg, int twoE) {
  int t = blockIdx.x * 256 + threadIdx.x;
  int stride = gridDim.x * 256;
  for (; t < twoE; t += stride) atomicAdd(&deg[eix[t]], 1u);
}

__global__ __launch_bounds__(1024) void scan_kernel(const u32* __restrict__ deg,
    u32* __restrict__ rowstart, u32* __restrict__ cursor, int N) {
  __shared__ u32 part[1024];
  const int t = threadIdx.x;
  const int chunk = (N + 1023) >> 10;
  const int b = t * chunk;
  const int e = min(b + chunk, N);
  u32 s = 0;
  for (int i = b; i < e; ++i) s += deg[i];
  part[t] = s;
  __syncthreads();
  for (int off = 1; off < 1024; off <<= 1) {
    u32 v = (t >= off) ? part[t - off] : 0u;
    __syncthreads();
    part[t] += v;
    __syncthreads();
  }
  u32 run = (t == 0) ? 0u : part[t - 1];
  for (int i = b; i < e; ++i) {
    rowstart[i] = run;
    cursor[i] = run;
    run += deg[i];
  }
  if (t == 1023) rowstart[N] = part[1023];
}

__global__ __launch_bounds__(256) void scatter_kernel(const int* __restrict__ eix,
    u32* __restrict__ cursor, uint2* __restrict__ adj, int E) {
  int t = blockIdx.x * 256 + threadIdx.x;
  int stride = gridDim.x * 256;
  int twoE = 2 * E;
  for (; t < twoE; t += stride) {
    int node, eid, other;
    if (t < E) { node = eix[t];     eid = t;     other = eix[t + E]; }
    else       { node = eix[t];     eid = t - E; other = eix[t - E]; }
    u32 pos = atomicAdd(&cursor[node], 1u);
    adj[pos] = make_uint2((u32)eid, (u32)other);
  }
}

// ---- fused gather + instance-norm + residual ----
// one wave per node, lane handles 2 features. SB: read precomputed bf16 sigmoid.
template<bool SB>
__global__ __launch_bounds__(256) void gather_final(const float* __restrict__ x,
    const u16* __restrict__ h1, const u16* __restrict__ h2,
    const float* __restrict__ ef, const u16* __restrict__ sbf,
    const uint2* __restrict__ adj, const u32* __restrict__ rowstart,
    const float* __restrict__ g3, float* __restrict__ out, int N) {
  int row = (blockIdx.x * 256 + threadIdx.x) >> 6;
  if (row >= N) return;
  row = __builtin_amdgcn_readfirstlane(row);
  const int lane = threadIdx.x & 63;
  const int d0 = lane * 2;

  const u32 beg = rowstart[row];
  const u32 end = rowstart[row + 1];

  float dx = 0.f, dy = 0.f, ax = 0.f, ay = 0.f;
  for (u32 j = beg; j < end; ++j) {
    uint2 en = adj[j];  // wave-uniform
    float sx, sy;
    if (SB) {
      u32 su = *(const u32*)(sbf + (size_t)en.x * DD + d0);
      sx = bf2f((u16)(su & 0xffffu));
      sy = bf2f((u16)(su >> 16));
    } else {
      float2 e2 = *(const float2*)(ef + (size_t)en.x * DD + d0);
      sx = 1.f / (1.f + __expf(-e2.x));
      sy = 1.f / (1.f + __expf(-e2.y));
    }
    u32 hu = *(const u32*)(h2 + (size_t)en.y * DD + d0);
    float hx = bf2f((u16)(hu & 0xffffu));
    float hy = bf2f((u16)(hu >> 16));
    dx += sx; dy += sy;
    ax = fmaf(sx, hx, ax);
    ay = fmaf(sy, hy, ay);
  }

  const size_t base = (size_t)row * DD + d0;
  float2 xv = *(const float2*)(x + base);
  u32 h1u = *(const u32*)(h1 + base);
  float2 gv = *(const float2*)(g3 + d0);

  float i0 = bf2f((u16)(h1u & 0xffffu)) + ax / (dx + 1e-7f) + gv.x;
  float i1 = bf2f((u16)(h1u >> 16)) + ay / (dy + 1e-7f) + gv.y;

  float s = i0 + i1;
  float q = i0 * i0 + i1 * i1;
#pragma unroll
  for (int off = 32; off; off >>= 1) {
    s += __shfl_xor(s, off);
    q += __shfl_xor(q, off);
  }
  float mean = s * (1.f / 128.f);
  float var = q * (1.f / 128.f) - mean * mean;
  float rstd = rsqrtf(var + 1e-5f);
  float n0v = (i0 - mean) * rstd;
  float n1v = (i1 - mean) * rstd;
  float o0 = xv.x + (n0v > 0.f ? n0v : 0.f);
  float o1 = xv.y + (n1v > 0.f ? n1v : 0.f);
  *(float2*)(out + base) = make_float2(o0, o1);
}

extern "C" void kernel_launch(void* const* d_in, const int* in_sizes, int n_in,
                              void* d_out, int out_size, void* d_ws, size_t ws_size,
                              hipStream_t stream) {
  const float* x   = (const float*)d_in[0];
  const int*   eix = (const int*)d_in[1];
  const float* ef  = (const float*)d_in[2];
  const float* gf  = (const float*)d_in[3];
  const float* W1a = (const float*)d_in[4];
  const float* b1a = (const float*)d_in[5];
  const float* W1b = (const float*)d_in[6];
  const float* b1b = (const float*)d_in[7];
  const float* W2a = (const float*)d_in[8];
  const float* b2a = (const float*)d_in[9];
  const float* W2b = (const float*)d_in[10];
  const float* b2b = (const float*)d_in[11];
  const float* W3a = (const float*)d_in[12];
  const float* b3a = (const float*)d_in[13];
  const float* W3b = (const float*)d_in[14];
  const float* b3b = (const float*)d_in[15];

  const int N = in_sizes[0] / DD;
  const int E = in_sizes[2] / DD;

  char* p = (char*)d_ws;
  auto take = [&](size_t bytes) -> char* {
    char* r = p;
    p += (bytes + 255) & ~(size_t)255;
    return r;
  };
  u16* xb    = (u16*)take((size_t)N * DD * 2);
  u16* w1aT  = (u16*)take((size_t)DD * HH * 2);
  u16* w1bT  = (u16*)take((size_t)DD * HH * 2);
  u16* w2aT  = (u16*)take((size_t)DD * HH * 2);
  u16* w2bT  = (u16*)take((size_t)DD * HH * 2);
  u16* hidb  = (u16*)take((size_t)N * HH * 2);
  u16* h1b   = (u16*)take((size_t)N * DD * 2);
  u16* h2b   = (u16*)take((size_t)N * DD * 2);
  u32* deg   = (u32*)take((size_t)N * 4);
  u32* rowst = (u32*)take((size_t)(N + 1) * 4);
  u32* curs  = (u32*)take((size_t)N * 4);
  uint2* adj = (uint2*)take((size_t)2 * E * 8);
  float* g3  = (float*)take((size_t)DD * 4);
  // big one last, gated on ws_size
  size_t sBytes = (size_t)E * DD * 2;
  bool useS = ((size_t)(p - (char*)d_ws) + sBytes) <= ws_size;
  u16* sbf = useS ? (u16*)take(sBytes) : nullptr;

  hipMemsetAsync(deg, 0, (size_t)N * 4, stream);

  conv8_f32_bf16<<<2048, 256, 0, stream>>>(x, (uint4*)xb, N * DD / 8);
  transpose_w<<<128, 256, 0, stream>>>(W1a, w1aT, DD, HH);
  transpose_w<<<128, 256, 0, stream>>>(W1b, w1bT, HH, DD);
  transpose_w<<<128, 256, 0, stream>>>(W2a, w2aT, DD, HH);
  transpose_w<<<128, 256, 0, stream>>>(W2b, w2bT, HH, DD);
  if (useS) sigmoid8_f32_bf16<<<4096, 256, 0, stream>>>(ef, (uint4*)sbf, E * DD / 8);
  g3_kernel<<<1, 256, 0, stream>>>(gf, W3a, b3a, W3b, b3b, g3);

  // CSR build (only depends on eix)
  count_kernel<<<2048, 256, 0, stream>>>(eix, deg, 2 * E);
  scan_kernel<<<1, 1024, 0, stream>>>(deg, rowst, curs, N);
  scatter_kernel<<<2048, 256, 0, stream>>>(eix, curs, adj, E);

  // FCNN1: h1 = relu(x@W1a+b1a)@W1b + b1b
  gemm_w64<128, HH, true ><<<1024, 256, 0, stream>>>(xb,   w1aT, b1a, hidb, N);
  gemm_w64<256, DD, false><<< 512, 256, 0, stream>>>(hidb, w1bT, b1b, h1b,  N);
  // FCNN2: h2 = relu(x@W2a+b2a)@W2b + b2b
  gemm_w64<128, HH, true ><<<1024, 256, 0, stream>>>(xb,   w2aT, b2a, hidb, N);
  gemm_w64<256, DD, false><<< 512, 256, 0, stream>>>(hidb, w2bT, b2b, h2b,  N);

  if (useS)
    gather_final<true ><<<(N + 3) / 4, 256, 0, stream>>>(x, h1b, h2b, ef, sbf, adj,
                                                         rowst, g3, (float*)d_out, N);
  else
    gather_final<false><<<(N + 3) / 4, 256, 0, stream>>>(x, h1b, h2b, ef, nullptr, adj,
                                                         rowst, g3, (float*)d_out, N);
}

// Round 5
// 450.766 us; speedup vs baseline: 1.2875x; 1.2875x over previous
//
#include <hip/hip_runtime.h>
#include <math.h>

#define DD 128
#define HH 256

typedef __attribute__((ext_vector_type(8))) short bf16x8;
typedef __attribute__((ext_vector_type(4))) float f32x4;
typedef __attribute__((ext_vector_type(2))) float f32x2;
typedef unsigned short u16;
typedef unsigned int u32;

__device__ __forceinline__ float bf2f(u16 u) {
  union { u32 i; float f; } v; v.i = ((u32)u) << 16; return v.f;
}
__device__ __forceinline__ u16 f2bf(float f) {
  union { u32 i; float f; } v; v.f = f;
  u32 r = v.i + 0x7FFFu + ((v.i >> 16) & 1u);
  return (u16)(r >> 16);
}
__device__ __forceinline__ u32 pack2(float a, float b) {
  return (u32)f2bf(a) | ((u32)f2bf(b) << 16);
}

// vectorized f32 -> bf16 (8 elems/thread)
__global__ __launch_bounds__(256) void conv8_f32_bf16(const float* __restrict__ in,
                                                      uint4* __restrict__ out, int n8) {
  int i = blockIdx.x * 256 + threadIdx.x;
  int stride = gridDim.x * 256;
  for (; i < n8; i += stride) {
    const f32x4 a = ((const f32x4*)in)[i * 2];
    const f32x4 b = ((const f32x4*)in)[i * 2 + 1];
    out[i] = make_uint4(pack2(a.x, a.y), pack2(a.z, a.w),
                        pack2(b.x, b.y), pack2(b.z, b.w));
  }
}

// vectorized sigmoid(f32) -> bf16; ef reads nontemporal (don't evict sbf from L3)
__global__ __launch_bounds__(256) void sigmoid8_f32_bf16(const float* __restrict__ in,
                                                         uint4* __restrict__ out, int n8) {
  int i = blockIdx.x * 256 + threadIdx.x;
  int stride = gridDim.x * 256;
  for (; i < n8; i += stride) {
    const f32x4 a = __builtin_nontemporal_load(((const f32x4*)in) + i * 2);
    const f32x4 b = __builtin_nontemporal_load(((const f32x4*)in) + i * 2 + 1);
    float s0 = 1.f / (1.f + __expf(-a.x));
    float s1 = 1.f / (1.f + __expf(-a.y));
    float s2 = 1.f / (1.f + __expf(-a.z));
    float s3 = 1.f / (1.f + __expf(-a.w));
    float s4 = 1.f / (1.f + __expf(-b.x));
    float s5 = 1.f / (1.f + __expf(-b.y));
    float s6 = 1.f / (1.f + __expf(-b.z));
    float s7 = 1.f / (1.f + __expf(-b.w));
    out[i] = make_uint4(pack2(s0, s1), pack2(s2, s3), pack2(s4, s5), pack2(s6, s7));
  }
}

// all 4 weight transposes in one launch: [K][N] f32 -> [N][K] bf16
__global__ __launch_bounds__(256) void transpose_all(
    const float* __restrict__ W1a, const float* __restrict__ W1b,
    const float* __restrict__ W2a, const float* __restrict__ W2b,
    u16* __restrict__ o1, u16* __restrict__ o2,
    u16* __restrict__ o3, u16* __restrict__ o4) {
  const int total = 4 * DD * HH;
  int idx = blockIdx.x * 256 + threadIdx.x;
  int stride = gridDim.x * 256;
  for (; idx < total; idx += stride) {
    int m = idx >> 15;          // DD*HH = 32768
    int r = idx & 32767;
    const float* in; u16* out; int K, Nc;
    if (m == 0)      { in = W1a; out = o1; K = DD; Nc = HH; }
    else if (m == 1) { in = W1b; out = o2; K = HH; Nc = DD; }
    else if (m == 2) { in = W2a; out = o3; K = DD; Nc = HH; }
    else             { in = W2b; out = o4; K = HH; Nc = DD; }
    int k = r / Nc, n = r % Nc;
    out[n * K + k] = f2bf(in[r]);
  }
}

// tiny FCNN on the global feature vector (fp32, one block)
__global__ __launch_bounds__(256) void g3_kernel(const float* __restrict__ g,
    const float* __restrict__ W3a, const float* __restrict__ b3a,
    const float* __restrict__ W3b, const float* __restrict__ b3b,
    float* __restrict__ g3out) {
  __shared__ float gs[DD];
  __shared__ float hs[HH];
  int t = threadIdx.x;
  if (t < DD) gs[t] = g[t];
  __syncthreads();
  float acc = b3a[t];
  for (int k = 0; k < DD; ++k) acc = fmaf(gs[k], W3a[k * HH + t], acc);
  hs[t] = acc > 0.f ? acc : 0.f;
  __syncthreads();
  if (t < DD) {
    float o = b3b[t];
    for (int j = 0; j < HH; ++j) o = fmaf(hs[j], W3b[j * DD + t], o);
    g3out[t] = o;
  }
}

// C[M,NCOLS] = A[M,K] @ B + bias (optional relu); BT = B^T [NCOLS][K] bf16.
// One wave: 16 rows x 64 cols, grid-stride over m-tiles.
template<int K, int NCOLS, bool RELU>
__global__ __launch_bounds__(256) void gemm_w64(const u16* __restrict__ A,
    const u16* __restrict__ BT, const float* __restrict__ bias,
    u16* __restrict__ Dst, int M) {
  const int wave = (blockIdx.x * 256 + threadIdx.x) >> 6;
  const int lane = threadIdx.x & 63;
  const int totalWaves = (gridDim.x * 256) >> 6;
  constexpr int nChunks = NCOLS / 64;
  const int nc = wave % nChunks;
  const int mw = wave / nChunks;
  const int mStride = totalWaves / nChunks;
  const int l15 = lane & 15;
  const int l4 = lane >> 4;
  constexpr int KB = K / 32;

  bf16x8 bfrag[KB][4];
  float bcol[4];
#pragma unroll
  for (int t = 0; t < 4; ++t) {
    const int col = nc * 64 + t * 16 + l15;
    const u16* bbase = BT + (size_t)col * K + l4 * 8;
#pragma unroll
    for (int kb = 0; kb < KB; ++kb) bfrag[kb][t] = *(const bf16x8*)(bbase + kb * 32);
    bcol[t] = bias[col];
  }

  const int mTiles = M >> 4;  // M multiple of 16
  for (int mt = mw; mt < mTiles; mt += mStride) {
    const int m0 = mt << 4;
    const u16* arow = A + (size_t)(m0 + l15) * K + l4 * 8;
    f32x4 acc[4] = {{0,0,0,0},{0,0,0,0},{0,0,0,0},{0,0,0,0}};
#pragma unroll
    for (int kb = 0; kb < KB; ++kb) {
      bf16x8 afrag = *(const bf16x8*)(arow + kb * 32);
#pragma unroll
      for (int t = 0; t < 4; ++t)
        acc[t] = __builtin_amdgcn_mfma_f32_16x16x32_bf16(afrag, bfrag[kb][t], acc[t], 0, 0, 0);
    }
#pragma unroll
    for (int t = 0; t < 4; ++t) {
#pragma unroll
      for (int r = 0; r < 4; ++r) {
        const int row = m0 + l4 * 4 + r;
        float v = acc[t][r] + bcol[t];
        if (RELU) v = v > 0.f ? v : 0.f;
        Dst[(size_t)row * NCOLS + nc * 64 + t * 16 + l15] = f2bf(v);
      }
    }
  }
}

// ---- CSR build ----
__global__ __launch_bounds__(256) void count_kernel(const int* __restrict__ eix,
                                                    u32* __restrict__ deg, int twoE) {
  int t = blockIdx.x * 256 + threadIdx.x;
  int stride = gridDim.x * 256;
  for (; t < twoE; t += stride) atomicAdd(&deg[eix[t]], 1u);
}

// 16-wave coalesced two-pass scan (single block)
__global__ __launch_bounds__(1024) void scan_kernel(const u32* __restrict__ deg,
    u32* __restrict__ rowstart, u32* __restrict__ cursor, int N) {
  __shared__ u32 wsum[16];
  const int t = threadIdx.x;
  const int w = t >> 6, lane = t & 63;
  const int span = ((N + 1023) & ~1023) >> 4;   // multiple of 64
  const int b = w * span;
  const int e = min(b + span, N);

  // pass 1: per-wave sum, coalesced
  u32 s = 0;
  for (int i = b + lane; i < e; i += 64) s += deg[i];
#pragma unroll
  for (int off = 32; off; off >>= 1) s += __shfl_xor(s, off);
  if (lane == 0) wsum[w] = s;
  __syncthreads();

  u32 carry = 0;
  for (int i = 0; i < w; ++i) carry += wsum[i];

  // pass 2: 64-wide inclusive shfl-scan per group
  for (int i0 = b; i0 < e; i0 += 64) {
    int i = i0 + lane;
    u32 v = (i < e) ? deg[i] : 0u;
    u32 inc = v;
#pragma unroll
    for (int off = 1; off < 64; off <<= 1) {
      u32 u2 = __shfl_up(inc, off);
      if (lane >= off) inc += u2;
    }
    u32 excl = carry + inc - v;
    if (i < e) { rowstart[i] = excl; cursor[i] = excl; }
    carry += __shfl(inc, 63);
  }
  if (w == 15 && lane == 63) rowstart[N] = carry;
}

__global__ __launch_bounds__(256) void scatter_kernel(const int* __restrict__ eix,
    u32* __restrict__ cursor, uint2* __restrict__ adj, int E) {
  int t = blockIdx.x * 256 + threadIdx.x;
  int stride = gridDim.x * 256;
  int twoE = 2 * E;
  for (; t < twoE; t += stride) {
    int node, eid, other;
    if (t < E) { node = eix[t]; eid = t;     other = eix[t + E]; }
    else       { node = eix[t]; eid = t - E; other = eix[t - E]; }
    u32 pos = atomicAdd(&cursor[node], 1u);
    adj[pos] = make_uint2((u32)eid, (u32)other);
  }
}

// ---- fused gather + instance-norm + residual ----
#define ACC2(su, hu)                                        \
  {                                                         \
    float sx_ = bf2f((u16)((su) & 0xffffu));                \
    float sy_ = bf2f((u16)((su) >> 16));                    \
    dx += sx_; dy += sy_;                                   \
    ax = fmaf(sx_, bf2f((u16)((hu) & 0xffffu)), ax);        \
    ay = fmaf(sy_, bf2f((u16)((hu) >> 16)), ay);            \
  }

template<bool SB>
__global__ __launch_bounds__(256) void gather_final(const float* __restrict__ x,
    const u16* __restrict__ h1, const u16* __restrict__ h2,
    const float* __restrict__ ef, const u16* __restrict__ sbf,
    const uint2* __restrict__ adj, const u32* __restrict__ rowstart,
    const float* __restrict__ g3, float* __restrict__ out, int N) {
  int row0 = (blockIdx.x * 256 + threadIdx.x) >> 6;
  if (row0 >= N) return;
  const int row = __builtin_amdgcn_readfirstlane(row0);
  const int lane = threadIdx.x & 63;
  const int d0 = lane * 2;

  const u32 beg = rowstart[row];
  const u32 end = rowstart[row + 1];

  float dx = 0.f, dy = 0.f, ax = 0.f, ay = 0.f;
  u32 j = beg;
  if (SB) {
    for (; j + 4 <= end; j += 4) {
      const uint2 e0 = adj[j + 0];
      const uint2 e1 = adj[j + 1];
      const uint2 e2 = adj[j + 2];
      const uint2 e3 = adj[j + 3];
      u32 s0 = *(const u32*)(sbf + (size_t)e0.x * DD + d0);
      u32 h0 = *(const u32*)(h2  + (size_t)e0.y * DD + d0);
      u32 s1 = *(const u32*)(sbf + (size_t)e1.x * DD + d0);
      u32 h1v = *(const u32*)(h2 + (size_t)e1.y * DD + d0);
      u32 s2 = *(const u32*)(sbf + (size_t)e2.x * DD + d0);
      u32 h2v = *(const u32*)(h2 + (size_t)e2.y * DD + d0);
      u32 s3 = *(const u32*)(sbf + (size_t)e3.x * DD + d0);
      u32 h3v = *(const u32*)(h2 + (size_t)e3.y * DD + d0);
      ACC2(s0, h0) ACC2(s1, h1v) ACC2(s2, h2v) ACC2(s3, h3v)
    }
  }
  for (; j < end; ++j) {
    uint2 en = adj[j];
    u32 su, hu;
    if (SB) {
      su = *(const u32*)(sbf + (size_t)en.x * DD + d0);
    } else {
      f32x2 e2 = *(const f32x2*)(ef + (size_t)en.x * DD + d0);
      su = pack2(1.f / (1.f + __expf(-e2.x)), 1.f / (1.f + __expf(-e2.y)));
    }
    hu = *(const u32*)(h2 + (size_t)en.y * DD + d0);
    ACC2(su, hu)
  }

  const size_t base = (size_t)row * DD + d0;
  f32x2 xv = __builtin_nontemporal_load((const f32x2*)(x + base));
  u32 h1u = __builtin_nontemporal_load((const u32*)(h1 + base));
  f32x2 gv = *(const f32x2*)(g3 + d0);

  float i0 = bf2f((u16)(h1u & 0xffffu)) + ax / (dx + 1e-7f) + gv.x;
  float i1 = bf2f((u16)(h1u >> 16)) + ay / (dy + 1e-7f) + gv.y;

  float s = i0 + i1;
  float q = i0 * i0 + i1 * i1;
#pragma unroll
  for (int off = 32; off; off >>= 1) {
    s += __shfl_xor(s, off);
    q += __shfl_xor(q, off);
  }
  float mean = s * (1.f / 128.f);
  float var = q * (1.f / 128.f) - mean * mean;
  float rstd = rsqrtf(var + 1e-5f);
  float n0v = (i0 - mean) * rstd;
  float n1v = (i1 - mean) * rstd;
  f32x2 ov;
  ov.x = xv.x + (n0v > 0.f ? n0v : 0.f);
  ov.y = xv.y + (n1v > 0.f ? n1v : 0.f);
  __builtin_nontemporal_store(ov, (f32x2*)(out + base));
}

extern "C" void kernel_launch(void* const* d_in, const int* in_sizes, int n_in,
                              void* d_out, int out_size, void* d_ws, size_t ws_size,
                              hipStream_t stream) {
  const float* x   = (const float*)d_in[0];
  const int*   eix = (const int*)d_in[1];
  const float* ef  = (const float*)d_in[2];
  const float* gf  = (const float*)d_in[3];
  const float* W1a = (const float*)d_in[4];
  const float* b1a = (const float*)d_in[5];
  const float* W1b = (const float*)d_in[6];
  const float* b1b = (const float*)d_in[7];
  const float* W2a = (const float*)d_in[8];
  const float* b2a = (const float*)d_in[9];
  const float* W2b = (const float*)d_in[10];
  const float* b2b = (const float*)d_in[11];
  const float* W3a = (const float*)d_in[12];
  const float* b3a = (const float*)d_in[13];
  const float* W3b = (const float*)d_in[14];
  const float* b3b = (const float*)d_in[15];

  const int N = in_sizes[0] / DD;
  const int E = in_sizes[2] / DD;

  char* p = (char*)d_ws;
  auto take = [&](size_t bytes) -> char* {
    char* r = p;
    p += (bytes + 255) & ~(size_t)255;
    return r;
  };
  u16* xb    = (u16*)take((size_t)N * DD * 2);
  u16* w1aT  = (u16*)take((size_t)DD * HH * 2);
  u16* w1bT  = (u16*)take((size_t)DD * HH * 2);
  u16* w2aT  = (u16*)take((size_t)DD * HH * 2);
  u16* w2bT  = (u16*)take((size_t)DD * HH * 2);
  u16* hidb  = (u16*)take((size_t)N * HH * 2);
  u16* h1b   = (u16*)take((size_t)N * DD * 2);
  u16* h2b   = (u16*)take((size_t)N * DD * 2);
  u32* deg   = (u32*)take((size_t)N * 4);
  u32* rowst = (u32*)take((size_t)(N + 1) * 4);
  u32* curs  = (u32*)take((size_t)N * 4);
  uint2* adj = (uint2*)take((size_t)2 * E * 8);
  float* g3  = (float*)take((size_t)DD * 4);
  size_t sBytes = (size_t)E * DD * 2;
  bool useS = ((size_t)(p - (char*)d_ws) + sBytes) <= ws_size;
  u16* sbf = useS ? (u16*)take(sBytes) : nullptr;

  hipMemsetAsync(deg, 0, (size_t)N * 4, stream);

  conv8_f32_bf16<<<2048, 256, 0, stream>>>(x, (uint4*)xb, N * DD / 8);
  transpose_all<<<512, 256, 0, stream>>>(W1a, W1b, W2a, W2b, w1aT, w1bT, w2aT, w2bT);
  g3_kernel<<<1, 256, 0, stream>>>(gf, W3a, b3a, W3b, b3b, g3);

  // CSR build
  count_kernel<<<2048, 256, 0, stream>>>(eix, deg, 2 * E);
  scan_kernel<<<1, 1024, 0, stream>>>(deg, rowst, curs, N);
  scatter_kernel<<<2048, 256, 0, stream>>>(eix, curs, adj, E);

  // FCNNs
  gemm_w64<128, HH, true ><<<1024, 256, 0, stream>>>(xb,   w1aT, b1a, hidb, N);
  gemm_w64<256, DD, false><<< 512, 256, 0, stream>>>(hidb, w1bT, b1b, h1b,  N);
  gemm_w64<128, HH, true ><<<1024, 256, 0, stream>>>(xb,   w2aT, b2a, hidb, N);
  gemm_w64<256, DD, false><<< 512, 256, 0, stream>>>(hidb, w2bT, b2b, h2b,  N);

  // sigmoid last so sbf is L3-resident for gather
  if (useS) sigmoid8_f32_bf16<<<4096, 256, 0, stream>>>(ef, (uint4*)sbf, E * DD / 8);

  if (useS)
    gather_final<true ><<<(N + 3) / 4, 256, 0, stream>>>(x, h1b, h2b, ef, sbf, adj,
                                                         rowst, g3, (float*)d_out, N);
  else
    gather_final<false><<<(N + 3) / 4, 256, 0, stream>>>(x, h1b, h2b, ef, nullptr, adj,
                                                         rowst, g3, (float*)d_out, N);
}